// Round 14
// baseline (1557.103 us; speedup 1.0000x reference)
//
#include <hip/hip_runtime.h>
#include <hip/hip_bf16.h>

// SwiGLU MLP: out = down( silu(x@Wg^T + bg) * (x@Wu^T + bu) ) + bd
// M=4096 tokens, H=4096, I=11008. fp32 in/out, bf16 MFMA compute.
// R14: weights consumed fp32 DIRECTLY (no cvt kernels for Wg/Wu/Wd) — fp32 loads
// issued early (chunk1), converted+ds_written late (chunk2) per T14 async-split.
// Everything else = R13: fused gate+up (256Mx128I), down (256x256), R11 semi-drift
// 2-sync/tile, counted vmcnt, no setprio, conflict-free XOR slot-swizzle,
// XCD-aware bijective block swizzle.

#define M_TOK 4096
#define HID   4096
#define INT_  11008

typedef __attribute__((ext_vector_type(8))) short bf16x8;
typedef __attribute__((ext_vector_type(4))) float f32x4;

__device__ __forceinline__ unsigned short f2bf(float f) {
    union { float f; unsigned int u; } a; a.f = f;
    unsigned int u = a.u;
    u += 0x7fff + ((u >> 16) & 1);   // RNE
    return (unsigned short)(u >> 16);
}

__device__ __forceinline__ bf16x8 pack8(f32x4 a, f32x4 b) {
    bf16x8 r;
    r[0] = (short)f2bf(a[0]); r[1] = (short)f2bf(a[1]);
    r[2] = (short)f2bf(a[2]); r[3] = (short)f2bf(a[3]);
    r[4] = (short)f2bf(b[0]); r[5] = (short)f2bf(b[1]);
    r[6] = (short)f2bf(b[2]); r[7] = (short)f2bf(b[3]);
    return r;
}

// ---------------- fp32 -> bf16 convert (x only) ----------------
__global__ void cvt_f32_bf16(const float* __restrict__ in, unsigned short* __restrict__ out, int n4) {
    int stride = gridDim.x * blockDim.x;
    for (int i = blockIdx.x * blockDim.x + threadIdx.x; i < n4; i += stride) {
        float4 v = ((const float4*)in)[i];
        ushort4 o;
        o.x = f2bf(v.x); o.y = f2bf(v.y); o.z = f2bf(v.z); o.w = f2bf(v.w);
        ((ushort4*)out)[i] = o;
    }
}

#define GLL(gsrc, ldst) \
    __builtin_amdgcn_global_load_lds( \
        (__attribute__((address_space(1))) void*)(gsrc), \
        (__attribute__((address_space(3))) void*)(ldst), 16, 0, 0)

#define VMC(n) asm volatile("s_waitcnt vmcnt(" #n ")" ::: "memory")
#define LGKM0  asm volatile("s_waitcnt lgkmcnt(0)" ::: "memory")
#define BARR __builtin_amdgcn_s_barrier()
#define PIN  __builtin_amdgcn_sched_barrier(0)

// load 2 slots (8 fp32 each) of one weight matrix into 4 f32x4 regs
#define WLOAD(DST, SRC, O0, O1) \
    DST[0] = *(const f32x4*)((SRC) + (O0));      \
    DST[1] = *(const f32x4*)((SRC) + (O0) + 4);  \
    DST[2] = *(const f32x4*)((SRC) + (O1));      \
    DST[3] = *(const f32x4*)((SRC) + (O1) + 4);

// convert + write the 2 slots to LDS (linear dest, matches GLL pattern)
#define WWRITE(BASE, SBUF, REGS) \
    *(bf16x8*)((SBUF) + (BASE) + tid * 8)        = pack8(REGS[0], REGS[1]); \
    *(bf16x8*)((SBUF) + (BASE) + 4096 + tid * 8) = pack8(REGS[2], REGS[3]);

// ================= FUSED gate+up: t = silu(x@Wg^T+bg) * (x@Wu^T+bu) =============
// x: M x K bf16 row-major (GLL-staged); Wg,Wu: I x K FP32 row-major (reg-staged
// with in-flight bf16 conversion); out t: M x I bf16.
// Tile 256(M) x 128(I), BK=64, 8 waves (2Mx4N).
// LDS/buffer (shorts): A-half0 [0,8192) A-half1 [8192,16384)
//                      Bg [16384,24576)  Bu [24576,32768).  dbuf = 128 KiB.
// Within a row, 16B slot s stored at s^(r&7) (0 bank conflicts, R9-verified).
__global__ __launch_bounds__(512, 2)
void gemm_gu(const unsigned short* __restrict__ A,
             const float* __restrict__ Wg,
             const float* __restrict__ Wu,
             const float* __restrict__ bg,
             const float* __restrict__ bu,
             unsigned short* __restrict__ T,
             int M, int NI, int K) {
    __shared__ unsigned short lds[2 * 32768];   // 128 KiB

    const int tid  = threadIdx.x;
    const int lane = tid & 63;
    const int w    = tid >> 6;
    const int wm   = w >> 2;
    const int wn   = w & 3;

    const int ntn = NI >> 7;                    // 86
    const int chunk = gridDim.x >> 3;
    const int sw = (blockIdx.x & 7) * chunk + (blockIdx.x >> 3);
    const int bm = sw / ntn, bn = sw % ntn;

    const unsigned short* Ag  = A  + (size_t)(bm * 256) * K;
    const float* Wgg = Wg + (size_t)(bn * 128) * K;
    const float* Wug = Wu + (size_t)(bn * 128) * K;

    // staging source offsets (pre-swizzled; LDS dest linear)
    int offA[2][2], offW[2];
#pragma unroll
    for (int i = 0; i < 2; ++i) {
        int sig = i * 512 + tid;
        int r   = sig >> 3;            // packed row 0..127
        int s   = (sig & 7) ^ (r & 7); // logical 16B-bf16 slot (8 elements)
#pragma unroll
        for (int h = 0; h < 2; ++h) {
            int grow = ((r >> 6) * 2 + h) * 64 + (r & 63);
            offA[h][i] = grow * K + s * 8;
        }
        offW[i] = r * K + s * 8;       // element offset (same for fp32)
    }

    const int rl = lane & 15;
    const int kg = lane >> 4;
    const int x  = rl & 7;
    const int aRow  = (wm * 64 + rl) * 64;
    const int bGoff = 16384 + (wn * 32 + rl) * 64;
    const int bUoff = 24576 + (wn * 32 + rl) * 64;
    int slt[2];
#pragma unroll
    for (int ks = 0; ks < 2; ++ks) slt[ks] = ((ks * 4 + kg) ^ x) * 8;

    f32x4 accg[2][8], accu[2][8];
#pragma unroll
    for (int q = 0; q < 2; ++q)
#pragma unroll
        for (int f = 0; f < 8; ++f) {
            accg[q][f] = (f32x4){0.f, 0.f, 0.f, 0.f};
            accu[q][f] = (f32x4){0.f, 0.f, 0.f, 0.f};
        }

    const int NT = K >> 6;

#define STAGE_A(H, DST, SRC) \
    GLL((SRC) + offA[H][0], (DST) + (H) * 8192 + tid * 8); \
    GLL((SRC) + offA[H][1], (DST) + (H) * 8192 + 4096 + tid * 8)
#define RD_A(BUF, QM, DST) \
    { _Pragma("unroll") for (int ks = 0; ks < 2; ++ks) \
      _Pragma("unroll") for (int fm = 0; fm < 4; ++fm) \
        DST[ks * 4 + fm] = *(const bf16x8*)((BUF) + (QM) * 8192 + aRow + fm * 1024 + slt[ks]); }
#define RD_W(BUF, ROFF, DST) \
    { _Pragma("unroll") for (int ks = 0; ks < 2; ++ks) \
      _Pragma("unroll") for (int fn = 0; fn < 2; ++fn) \
        DST[ks * 2 + fn] = *(const bf16x8*)((BUF) + (ROFF) + fn * 1024 + slt[ks]); }
#define Q16(ACC, QM, AF, BF) \
    { _Pragma("unroll") for (int ks = 0; ks < 2; ++ks) \
      _Pragma("unroll") for (int fm = 0; fm < 4; ++fm) \
      _Pragma("unroll") for (int fn = 0; fn < 2; ++fn) \
        ACC[QM][fm * 2 + fn] = __builtin_amdgcn_mfma_f32_16x16x32_bf16( \
            AF[ks * 4 + fm], BF[ks * 2 + fn], ACC[QM][fm * 2 + fn], 0, 0, 0); }

    bf16x8 A0f[8], A1f[8], Bgf[4], Buf_[4];
    f32x4 wgr[4], wur[4];

    // ---- prologue: tile 0 — weights via regs, A via GLL; one-time full drain ----
    WLOAD(wgr, Wgg, offW[0], offW[1]);
    WLOAD(wur, Wug, offW[0], offW[1]);
    PIN;                                   // VMEM group order: LW before GLL
    STAGE_A(0, lds, Ag);
    STAGE_A(1, lds, Ag);
    WWRITE(16384, lds, wgr);               // compiler waits the LW data here
    WWRITE(24576, lds, wur);
    VMC(0);                                // drain A GLLs (once)
    LGKM0;
    BARR; PIN;

    // ---- main loop: 2 chunks/tile; LW(t+1) issued c1, written c2 ----
    for (int t = 0; t < NT; ++t) {
        const unsigned short* bc = lds + (t & 1) * 32768;
        unsigned short* sb = lds + ((t + 1) & 1) * 32768;
        const int ts = (t + 1 < NT) ? (t + 1) : (NT - 1);
        const unsigned short* sA = Ag + (size_t)ts * 64;
        const float* sG = Wgg + (size_t)ts * 64;
        const float* sU = Wug + (size_t)ts * 64;

        // chunk1: ds_read A0+Bg+Bu | issue LW8(t+1) | GLL A0(t+1) | 32 MFMA
        RD_A(bc, 0, A0f);
        RD_W(bc, bGoff, Bgf);
        RD_W(bc, bUoff, Buf_);
        WLOAD(wgr, sG, offW[0], offW[1]);
        WLOAD(wur, sU, offW[0], offW[1]);
        PIN;                               // keep LW group before GLL group
        STAGE_A(0, sb, sA);
        Q16(accg, 0, A0f, Bgf);
        Q16(accu, 0, A0f, Buf_);
        VMC(10);                           // retires t.A1 (queue: LW8 + A0:2 left)
        BARR; PIN;

        // chunk2: ds_read A1 | GLL A1(t+1) | 32 MFMA | cvt+write W(t+1)
        RD_A(bc, 1, A1f);
        STAGE_A(1, sb, sA);
        Q16(accg, 1, A1f, Bgf);
        Q16(accu, 1, A1f, Buf_);
        VMC(4);                            // retires LW8 (leaves A0,A1 GLLs)
        WWRITE(16384, sb, wgr);
        WWRITE(24576, sb, wur);
        VMC(2);                            // retires A0(t+1)
        LGKM0;                             // ds_writes visible post-barrier
        BARR; PIN;
    }
#undef RD_A
#undef RD_W
#undef Q16
#undef STAGE_A

    // epilogue: C/D layout col=lane&15, row=(lane>>4)*4+j; t = silu(g)*u -> bf16
    const int rbase = bm * 256 + wm * 128 + (lane >> 4) * 4;
    const int cbase = bn * 128 + wn * 32 + (lane & 15);
#pragma unroll
    for (int qm = 0; qm < 2; ++qm)
#pragma unroll
        for (int fn = 0; fn < 2; ++fn) {
            const int col = cbase + fn * 16;
            const float bgv = bg[col];
            const float buv = bu[col];
#pragma unroll
            for (int fm = 0; fm < 4; ++fm) {
                const int rb = rbase + qm * 64 + fm * 16;
#pragma unroll
                for (int j = 0; j < 4; ++j) {
                    float g = accg[qm][fm * 2 + fn][j] + bgv;
                    float u = accu[qm][fm * 2 + fn][j] + buv;
                    float s = g / (1.f + __expf(-g)) * u;
                    T[(size_t)(rb + j) * (size_t)INT_ + col] = f2bf(s);
                }
            }
        }
}

// ================= down GEMM: out = t @ Wd^T + bd (Wd fp32 reg-staged) =========
// A: M x K bf16 row-major (GLL); B: Wd N x K FP32 row-major (reg-staged+cvt).
__global__ __launch_bounds__(512, 2)
void gemm_dn(const unsigned short* __restrict__ A,
             const float* __restrict__ B,
             const float* __restrict__ bias,
             float* __restrict__ C,
             int M, int N, int K) {
    __shared__ unsigned short lds[2 * 32768];   // 128 KiB

    const int tid  = threadIdx.x;
    const int lane = tid & 63;
    const int w    = tid >> 6;
    const int wm   = w >> 2;
    const int wn   = w & 3;

    const int ntn = N >> 8;
    const int chunk = gridDim.x >> 3;
    const int sw = (blockIdx.x & 7) * chunk + (blockIdx.x >> 3);
    const int bm = sw / ntn, bn = sw % ntn;

    const unsigned short* Ag = A + (size_t)(bm * 256) * K;
    const float* Bg = B + (size_t)(bn * 256) * K;

    int offA[2][2], offW[2][2];
#pragma unroll
    for (int h = 0; h < 2; ++h)
#pragma unroll
        for (int i = 0; i < 2; ++i) {
            int sig = i * 512 + tid;
            int r   = sig >> 3;
            int s   = (sig & 7) ^ (r & 7);
            int grow = ((r >> 6) * 2 + h) * 64 + (r & 63);
            int gcol = ((r >> 5) * 2 + h) * 32 + (r & 31);
            offA[h][i] = grow * K + s * 8;
            offW[h][i] = gcol * K + s * 8;     // element offset (fp32)
        }

    const int rl = lane & 15;
    const int kg = lane >> 4;
    const int x  = rl & 7;
    const int aRow = (wm * 64 + rl) * 64;
    const int bRow = 16384 + (wn * 32 + rl) * 64;
    int slt[2];
#pragma unroll
    for (int ks = 0; ks < 2; ++ks) slt[ks] = ((ks * 4 + kg) ^ x) * 8;

    f32x4 acc[2][2][8];
#pragma unroll
    for (int qm = 0; qm < 2; ++qm)
#pragma unroll
        for (int qn = 0; qn < 2; ++qn)
#pragma unroll
            for (int f = 0; f < 8; ++f)
                acc[qm][qn][f] = (f32x4){0.f, 0.f, 0.f, 0.f};

    const int NT = K >> 6;

#define STAGE_A(H, DST, SRC) \
    GLL((SRC) + offA[H][0], (DST) + (H) * 8192 + tid * 8); \
    GLL((SRC) + offA[H][1], (DST) + (H) * 8192 + 4096 + tid * 8)
#define RD_A(BUF, QM, DST) \
    { _Pragma("unroll") for (int ks = 0; ks < 2; ++ks) \
      _Pragma("unroll") for (int fm = 0; fm < 4; ++fm) \
        DST[ks * 4 + fm] = *(const bf16x8*)((BUF) + (QM) * 8192 + aRow + fm * 1024 + slt[ks]); }
#define RD_B(BUF, QN, DST) \
    { _Pragma("unroll") for (int ks = 0; ks < 2; ++ks) \
      _Pragma("unroll") for (int fn = 0; fn < 2; ++fn) \
        DST[ks * 2 + fn] = *(const bf16x8*)((BUF) + (QN) * 8192 + bRow + fn * 1024 + slt[ks]); }
#define Q16(QM, QN, AF, BF) \
    { _Pragma("unroll") for (int ks = 0; ks < 2; ++ks) \
      _Pragma("unroll") for (int fm = 0; fm < 4; ++fm) \
      _Pragma("unroll") for (int fn = 0; fn < 2; ++fn) \
        acc[QM][QN][fm * 2 + fn] = __builtin_amdgcn_mfma_f32_16x16x32_bf16( \
            AF[ks * 4 + fm], BF[ks * 2 + fn], acc[QM][QN][fm * 2 + fn], 0, 0, 0); }

    bf16x8 A0f[8], A1f[8], B0f[4], B1f[4];
    f32x4 w0[4], w1[4];

    // ---- prologue: tile 0 ----
    WLOAD(w0, Bg, offW[0][0], offW[0][1]);
    WLOAD(w1, Bg, offW[1][0], offW[1][1]);
    PIN;
    STAGE_A(0, lds, Ag);
    STAGE_A(1, lds, Ag);
    WWRITE(16384, lds, w0);
    WWRITE(24576, lds, w1);
    VMC(0);
    LGKM0;
    BARR; PIN;

    for (int t = 0; t < NT; ++t) {
        const unsigned short* bc = lds + (t & 1) * 32768;
        unsigned short* sb = lds + ((t + 1) & 1) * 32768;
        const int ts = (t + 1 < NT) ? (t + 1) : (NT - 1);
        const unsigned short* sAt = Ag + (size_t)ts * 64;
        const float* sBt = Bg + (size_t)ts * 64;

        // chunk1
        RD_A(bc, 0, A0f);
        RD_B(bc, 0, B0f);
        WLOAD(w0, sBt, offW[0][0], offW[0][1]);
        WLOAD(w1, sBt, offW[1][0], offW[1][1]);
        PIN;
        STAGE_A(0, sb, sAt);
        Q16(0, 0, A0f, B0f);
        RD_B(bc, 1, B1f);
        Q16(0, 1, A0f, B1f);
        VMC(10);                           // retires t.A1
        BARR; PIN;

        // chunk2
        RD_A(bc, 1, A1f);
        STAGE_A(1, sb, sAt);
        Q16(1, 1, A1f, B1f);
        Q16(1, 0, A1f, B0f);
        VMC(4);                            // retires LW8
        WWRITE(16384, sb, w0);
        WWRITE(24576, sb, w1);
        VMC(2);                            // retires A0(t+1)
        LGKM0;
        BARR; PIN;
    }
#undef RD_A
#undef RD_B
#undef Q16
#undef STAGE_A

    const int rbase = bm * 256 + wm * 128 + (lane >> 4) * 4;
    const int cbase = bn * 256 + wn * 64 + (lane & 15);
#pragma unroll
    for (int qm = 0; qm < 2; ++qm)
#pragma unroll
        for (int qn = 0; qn < 2; ++qn)
#pragma unroll
            for (int fn = 0; fn < 2; ++fn) {
                const int col = cbase + qn * 32 + fn * 16;
                const float bv = bias[col];
#pragma unroll
                for (int fm = 0; fm < 4; ++fm) {
                    const int rb = rbase + qm * 64 + fm * 16;
#pragma unroll
                    for (int j = 0; j < 4; ++j)
                        C[(size_t)(rb + j) * (size_t)N + col] = acc[qm][qn][fm * 2 + fn][j] + bv;
                }
            }
}

// ---------------- launcher ----------------
extern "C" void kernel_launch(void* const* d_in, const int* in_sizes, int n_in,
                              void* d_out, int out_size, void* d_ws, size_t ws_size,
                              hipStream_t stream) {
    const float* x  = (const float*)d_in[0];   // (2,2048,4096)
    const float* wg = (const float*)d_in[1];   // (11008,4096) fp32
    const float* bg = (const float*)d_in[2];
    const float* wu = (const float*)d_in[3];
    const float* bu = (const float*)d_in[4];
    const float* wd = (const float*)d_in[5];   // (4096,11008) fp32
    const float* bd = (const float*)d_in[6];

    const size_t NX = (size_t)M_TOK * HID;     // 16,777,216
    const size_t NW = (size_t)M_TOK * INT_;    // 45,088,768

    unsigned short* ws = (unsigned short*)d_ws;
    unsigned short* Xb = ws;                   // x bf16
    unsigned short* Tt = Xb + NX;              // t = silu(g)*u bf16
    // ws need: (NX + NW)*2 = 123,731,968 bytes

    dim3 blk512(512);
    dim3 blk256(256);

    cvt_f32_bf16<<<2048, blk256, 0, stream>>>(x, Xb, (int)(NX / 4));
    // fused gate+up: t = silu(x@Wg^T+bg)*(x@Wu^T+bu)  grid 16*86=1376 (%8==0)
    gemm_gu<<<dim3(16 * 86), blk512, 0, stream>>>(Xb, wg, wu, bg, bu, Tt,
                                                  M_TOK, INT_, HID);
    // down: out = t @ Wd^T + bd  (fp32)  grid 16*16=256 (%8==0), NT=172
    gemm_dn<<<dim3(16 * 16), blk512, 0, stream>>>(Tt, wd, bd, (float*)d_out,
                                                  M_TOK, HID, INT_);
}

// Round 15
// 1022.313 us; speedup vs baseline: 1.5231x; 1.5231x over previous
//
#include <hip/hip_runtime.h>
#include <hip/hip_bf16.h>

// SwiGLU MLP: out = down( silu(x@Wg^T + bg) * (x@Wu^T + bu) ) + bd
// M=4096 tokens, H=4096, I=11008. fp32 in/out, bf16 MFMA compute.
// R15 = R13 (bf16 weights via cvt kernels — fp32-direct R14 thrashed L3, 2.9GB
// fetch) + ONE change: gu block mapping is bm-MINOR within each XCD chunk, so
// the 32 co-resident blocks of an XCD share one weight panel (2MB bf16, L2-fits)
// and stream x (32MB, L3-resident) instead of streaming the 180MB weight set.
// Fused gate+up (256Mx128I) + down (256x256), R11 semi-drift 2-sync/tile,
// counted vmcnt, no setprio, conflict-free XOR slot-swizzle, XCD bijective swizzle.

#define M_TOK 4096
#define HID   4096
#define INT_  11008

typedef __attribute__((ext_vector_type(8))) short bf16x8;
typedef __attribute__((ext_vector_type(4))) float f32x4;

__device__ __forceinline__ unsigned short f2bf(float f) {
    union { float f; unsigned int u; } a; a.f = f;
    unsigned int u = a.u;
    u += 0x7fff + ((u >> 16) & 1);   // RNE
    return (unsigned short)(u >> 16);
}

__device__ __forceinline__ float bf2f(unsigned short h) {
    union { unsigned int u; float f; } a; a.u = ((unsigned int)h) << 16;
    return a.f;
}

// ---------------- fp32 -> bf16 convert (vectorized, grid-stride) ----------------
__global__ void cvt_f32_bf16(const float* __restrict__ in, unsigned short* __restrict__ out, int n4) {
    int stride = gridDim.x * blockDim.x;
    for (int i = blockIdx.x * blockDim.x + threadIdx.x; i < n4; i += stride) {
        float4 v = ((const float4*)in)[i];
        ushort4 o;
        o.x = f2bf(v.x); o.y = f2bf(v.y); o.z = f2bf(v.z); o.w = f2bf(v.w);
        ((ushort4*)out)[i] = o;
    }
}

#define GLL(gsrc, ldst) \
    __builtin_amdgcn_global_load_lds( \
        (__attribute__((address_space(1))) void*)(gsrc), \
        (__attribute__((address_space(3))) void*)(ldst), 16, 0, 0)

#define VMC(n) asm volatile("s_waitcnt vmcnt(" #n ")" ::: "memory")
#define BARR __builtin_amdgcn_s_barrier()
#define PIN  __builtin_amdgcn_sched_barrier(0)

// ================= FUSED gate+up: t = silu(x@Wg^T+bg) * (x@Wu^T+bu) =============
// x: M x K bf16 row-major; Wg,Wu: I x K bf16 row-major; out t: M x I bf16.
// Tile 256(M) x 128(I), BK=64, 8 waves (2Mx4N; per-wave 128x32, both gemms).
// LDS/buffer (shorts): A-half0 [0,8192) A-half1 [8192,16384)
//                      Bg [16384,24576)  Bu [24576,32768).  dbuf = 128 KiB.
// Within a row, 16B slot s stored at s^(r&7) (0 bank conflicts, R9-verified).
__global__ __launch_bounds__(512, 2)
void gemm_gu(const unsigned short* __restrict__ A,
             const unsigned short* __restrict__ Wg,
             const unsigned short* __restrict__ Wu,
             const float* __restrict__ bg,
             const float* __restrict__ bu,
             unsigned short* __restrict__ T,
             int M, int NI, int K) {
    __shared__ unsigned short lds[2 * 32768];   // 128 KiB

    const int tid  = threadIdx.x;
    const int lane = tid & 63;
    const int w    = tid >> 6;
    const int wm   = w >> 2;         // 0..1  (128 rows)
    const int wn   = w & 3;          // 0..3  (32 inter-cols)

    // XCD-aware bijective swizzle (grid % 8 == 0), bm-MINOR within chunk:
    // the ~32 co-resident blocks of an XCD share the same bn (weight panel
    // Wg+Wu = 2MB bf16 -> L2-resident) and walk bm (x panels stream via L3).
    const int nbm = M >> 8;                     // 16
    const int chunk = gridDim.x >> 3;
    const int sw = (blockIdx.x & 7) * chunk + (blockIdx.x >> 3);
    const int bm = sw % nbm, bn = sw / nbm;

    const unsigned short* Ag  = A  + (size_t)(bm * 256) * K;
    const unsigned short* Bgg = Wg + (size_t)(bn * 128) * K;
    const unsigned short* Bug = Wu + (size_t)(bn * 128) * K;

    // staging source offsets (pre-swizzled; LDS dest linear)
    int offA[2][2], offBW[2];
#pragma unroll
    for (int i = 0; i < 2; ++i) {
        int sig = i * 512 + tid;
        int r   = sig >> 3;            // packed row 0..127
        int s   = (sig & 7) ^ (r & 7); // logical 16B slot
#pragma unroll
        for (int h = 0; h < 2; ++h) {
            int grow = ((r >> 6) * 2 + h) * 64 + (r & 63);
            offA[h][i] = grow * K + s * 8;
        }
        offBW[i] = r * K + s * 8;      // B rows map 1:1
    }

    // ds_read fragment addressing (swizzled slots)
    const int rl = lane & 15;
    const int kg = lane >> 4;
    const int x  = rl & 7;
    const int aRow  = (wm * 64 + rl) * 64;
    const int bGoff = 16384 + (wn * 32 + rl) * 64;
    const int bUoff = 24576 + (wn * 32 + rl) * 64;
    int slt[2];
#pragma unroll
    for (int ks = 0; ks < 2; ++ks) slt[ks] = ((ks * 4 + kg) ^ x) * 8;

    f32x4 accg[2][8], accu[2][8];     // [qm][fm*2+fn]
#pragma unroll
    for (int q = 0; q < 2; ++q)
#pragma unroll
        for (int f = 0; f < 8; ++f) {
            accg[q][f] = (f32x4){0.f, 0.f, 0.f, 0.f};
            accu[q][f] = (f32x4){0.f, 0.f, 0.f, 0.f};
        }

    const int NT = K >> 6;

#define STAGE_A(H, DST, SRC) \
    GLL((SRC) + offA[H][0], (DST) + (H) * 8192 + tid * 8); \
    GLL((SRC) + offA[H][1], (DST) + (H) * 8192 + 4096 + tid * 8)
#define STAGE_W(BASE, DST, SRC) \
    GLL((SRC) + offBW[0], (DST) + (BASE) + tid * 8); \
    GLL((SRC) + offBW[1], (DST) + (BASE) + 4096 + tid * 8)

#define RD_A(BUF, QM, DST) \
    { _Pragma("unroll") for (int ks = 0; ks < 2; ++ks) \
      _Pragma("unroll") for (int fm = 0; fm < 4; ++fm) \
        DST[ks * 4 + fm] = *(const bf16x8*)((BUF) + (QM) * 8192 + aRow + fm * 1024 + slt[ks]); }
#define RD_W(BUF, ROFF, DST) \
    { _Pragma("unroll") for (int ks = 0; ks < 2; ++ks) \
      _Pragma("unroll") for (int fn = 0; fn < 2; ++fn) \
        DST[ks * 2 + fn] = *(const bf16x8*)((BUF) + (ROFF) + fn * 1024 + slt[ks]); }
#define Q16(ACC, QM, AF, BF) \
    { _Pragma("unroll") for (int ks = 0; ks < 2; ++ks) \
      _Pragma("unroll") for (int fm = 0; fm < 4; ++fm) \
      _Pragma("unroll") for (int fn = 0; fn < 2; ++fn) \
        ACC[QM][fm * 2 + fn] = __builtin_amdgcn_mfma_f32_16x16x32_bf16( \
            AF[ks * 4 + fm], BF[ks * 2 + fn], ACC[QM][fm * 2 + fn], 0, 0, 0); }

    bf16x8 A0f[8], A1f[8], Bgf[4], Buf_[4];

    // prologue: stage tile 0 as A0,Bg,Bu,A1; establish invariant (only A1 in flight)
    STAGE_A(0, lds, Ag);
    STAGE_W(16384, lds, Bgg);
    STAGE_W(24576, lds, Bug);
    STAGE_A(1, lds, Ag);
    VMC(2);
    BARR; PIN;

    for (int t = 0; t < NT; ++t) {
        const unsigned short* bc = lds + (t & 1) * 32768;
        unsigned short* sb = lds + ((t + 1) & 1) * 32768;
        const int ts = (t + 1 < NT) ? (t + 1) : (NT - 1);
        const unsigned short* sA = Ag + (size_t)ts * 64;
        const unsigned short* sG = Bgg + (size_t)ts * 64;
        const unsigned short* sU = Bug + (size_t)ts * 64;

        // chunk1: A0,Bg,Bu proven; 32 MFMA; stage A0,Bg,Bu(t+1)
        RD_A(bc, 0, A0f);
        RD_W(bc, bGoff, Bgf);
        STAGE_A(0, sb, sA);
        Q16(accg, 0, A0f, Bgf);
        RD_W(bc, bUoff, Buf_);
        STAGE_W(16384, sb, sG);
        Q16(accu, 0, A0f, Buf_);
        STAGE_W(24576, sb, sU);
        VMC(6);                         // retires t.A1
        BARR; PIN;

        // chunk2: A1 proven; 32 MFMA; stage A1(t+1)
        RD_A(bc, 1, A1f);
        STAGE_A(1, sb, sA);
        Q16(accg, 1, A1f, Bgf);
        Q16(accu, 1, A1f, Buf_);
        VMC(2);                         // retires t+1.A0,Bg,Bu
        BARR; PIN;
    }
#undef RD_A
#undef RD_W
#undef Q16
#undef STAGE_A
#undef STAGE_W

    // epilogue: C/D layout col=lane&15, row=(lane>>4)*4+j; t = silu(g)*u -> bf16
    const int rbase = bm * 256 + wm * 128 + (lane >> 4) * 4;
    const int cbase = bn * 128 + wn * 32 + (lane & 15);
#pragma unroll
    for (int qm = 0; qm < 2; ++qm)
#pragma unroll
        for (int fn = 0; fn < 2; ++fn) {
            const int col = cbase + fn * 16;
            const float bgv = bg[col];
            const float buv = bu[col];
#pragma unroll
            for (int fm = 0; fm < 4; ++fm) {
                const int rb = rbase + qm * 64 + fm * 16;
#pragma unroll
                for (int j = 0; j < 4; ++j) {
                    float g = accg[qm][fm * 2 + fn][j] + bgv;
                    float u = accu[qm][fm * 2 + fn][j] + buv;
                    float s = g / (1.f + __expf(-g)) * u;
                    T[(size_t)(rb + j) * (size_t)INT_ + col] = f2bf(s);
                }
            }
        }
}

// ================= down GEMM (R11 verbatim, fp32 epilogue) ======================
// A: M x K bf16 row-major; B: N x K bf16 row-major; C fp32 = A*B^T + bias.
__global__ __launch_bounds__(512, 2)
void gemm_dn(const unsigned short* __restrict__ A,
             const unsigned short* __restrict__ B,
             const float* __restrict__ bias,
             float* __restrict__ C,
             int M, int N, int K) {
    __shared__ unsigned short lds[2 * 32768];   // 128 KiB

    const int tid  = threadIdx.x;
    const int lane = tid & 63;
    const int w    = tid >> 6;
    const int wm   = w >> 2;
    const int wn   = w & 3;

    const int ntn = N >> 8;
    const int chunk = gridDim.x >> 3;
    const int sw = (blockIdx.x & 7) * chunk + (blockIdx.x >> 3);
    const int bm = sw / ntn, bn = sw % ntn;

    const unsigned short* Ag = A + (size_t)(bm * 256) * K;
    const unsigned short* Bg = B + (size_t)(bn * 256) * K;

    int offA[2][2], offB[2][2];
#pragma unroll
    for (int h = 0; h < 2; ++h)
#pragma unroll
        for (int i = 0; i < 2; ++i) {
            int sig = i * 512 + tid;
            int r   = sig >> 3;
            int s   = (sig & 7) ^ (r & 7);
            int grow = ((r >> 6) * 2 + h) * 64 + (r & 63);
            int gcol = ((r >> 5) * 2 + h) * 32 + (r & 31);
            offA[h][i] = grow * K + s * 8;
            offB[h][i] = gcol * K + s * 8;
        }

    const int rl = lane & 15;
    const int kg = lane >> 4;
    const int x  = rl & 7;
    const int aRow = (wm * 64 + rl) * 64;
    const int bRow = 16384 + (wn * 32 + rl) * 64;
    int slt[2];
#pragma unroll
    for (int ks = 0; ks < 2; ++ks) slt[ks] = ((ks * 4 + kg) ^ x) * 8;

    f32x4 acc[2][2][8];
#pragma unroll
    for (int qm = 0; qm < 2; ++qm)
#pragma unroll
        for (int qn = 0; qn < 2; ++qn)
#pragma unroll
            for (int f = 0; f < 8; ++f)
                acc[qm][qn][f] = (f32x4){0.f, 0.f, 0.f, 0.f};

    const int NT = K >> 6;

#define STAGE_A(H, DST, SRC) \
    GLL((SRC) + offA[H][0], (DST) + (H) * 8192 + tid * 8); \
    GLL((SRC) + offA[H][1], (DST) + (H) * 8192 + 4096 + tid * 8)
#define STAGE_B(H, DST, SRC) \
    GLL((SRC) + offB[H][0], (DST) + 16384 + (H) * 8192 + tid * 8); \
    GLL((SRC) + offB[H][1], (DST) + 16384 + (H) * 8192 + 4096 + tid * 8)
#define RD_A(BUF, QM, DST) \
    { _Pragma("unroll") for (int ks = 0; ks < 2; ++ks) \
      _Pragma("unroll") for (int fm = 0; fm < 4; ++fm) \
        DST[ks * 4 + fm] = *(const bf16x8*)((BUF) + (QM) * 8192 + aRow + fm * 1024 + slt[ks]); }
#define RD_B(BUF, QN, DST) \
    { _Pragma("unroll") for (int ks = 0; ks < 2; ++ks) \
      _Pragma("unroll") for (int fn = 0; fn < 2; ++fn) \
        DST[ks * 2 + fn] = *(const bf16x8*)((BUF) + (QN) * 8192 + bRow + fn * 1024 + slt[ks]); }
#define Q16(QM, QN, AF, BF) \
    { _Pragma("unroll") for (int ks = 0; ks < 2; ++ks) \
      _Pragma("unroll") for (int fm = 0; fm < 4; ++fm) \
      _Pragma("unroll") for (int fn = 0; fn < 2; ++fn) \
        acc[QM][QN][fm * 2 + fn] = __builtin_amdgcn_mfma_f32_16x16x32_bf16( \
            AF[ks * 4 + fm], BF[ks * 2 + fn], acc[QM][QN][fm * 2 + fn], 0, 0, 0); }

    bf16x8 A0f[8], A1f[8], B0f[4], B1f[4];

    STAGE_A(0, lds, Ag); STAGE_B(0, lds, Bg); STAGE_B(1, lds, Bg); STAGE_A(1, lds, Ag);
    VMC(2);
    BARR; PIN;

    for (int t = 0; t < NT; ++t) {
        const unsigned short* bc = lds + (t & 1) * 32768;
        unsigned short* sb = lds + ((t + 1) & 1) * 32768;
        const int ts = (t + 1 < NT) ? (t + 1) : (NT - 1);
        const unsigned short* sAt = Ag + (size_t)ts * 64;
        const unsigned short* sBt = Bg + (size_t)ts * 64;

        RD_A(bc, 0, A0f);
        RD_B(bc, 0, B0f);
        STAGE_A(0, sb, sAt);
        Q16(0, 0, A0f, B0f);
        RD_B(bc, 1, B1f);
        STAGE_B(0, sb, sBt);
        Q16(0, 1, A0f, B1f);
        STAGE_B(1, sb, sBt);
        VMC(6);
        BARR; PIN;

        RD_A(bc, 1, A1f);
        STAGE_A(1, sb, sAt);
        Q16(1, 1, A1f, B1f);
        Q16(1, 0, A1f, B0f);
        VMC(2);
        BARR; PIN;
    }
#undef RD_A
#undef RD_B
#undef Q16
#undef STAGE_A
#undef STAGE_B

    const int rbase = bm * 256 + wm * 128 + (lane >> 4) * 4;
    const int cbase = bn * 256 + wn * 64 + (lane & 15);
#pragma unroll
    for (int qm = 0; qm < 2; ++qm)
#pragma unroll
        for (int qn = 0; qn < 2; ++qn)
#pragma unroll
            for (int fn = 0; fn < 2; ++fn) {
                const int col = cbase + qn * 32 + fn * 16;
                const float bv = bias[col];
#pragma unroll
                for (int fm = 0; fm < 4; ++fm) {
                    const int rb = rbase + qm * 64 + fm * 16;
#pragma unroll
                    for (int j = 0; j < 4; ++j)
                        C[(size_t)(rb + j) * (size_t)N + col] = acc[qm][qn][fm * 2 + fn][j] + bv;
                }
            }
}

// ---------------- launcher ----------------
extern "C" void kernel_launch(void* const* d_in, const int* in_sizes, int n_in,
                              void* d_out, int out_size, void* d_ws, size_t ws_size,
                              hipStream_t stream) {
    const float* x  = (const float*)d_in[0];   // (2,2048,4096)
    const float* wg = (const float*)d_in[1];   // (11008,4096)
    const float* bg = (const float*)d_in[2];
    const float* wu = (const float*)d_in[3];
    const float* bu = (const float*)d_in[4];
    const float* wd = (const float*)d_in[5];   // (4096,11008)
    const float* bd = (const float*)d_in[6];

    const size_t NX = (size_t)M_TOK * HID;     // 16,777,216
    const size_t NW = (size_t)INT_ * HID;      // 45,088,768 (== M_TOK*INT_)

    unsigned short* ws = (unsigned short*)d_ws;
    unsigned short* Xb = ws;                   // x bf16
    unsigned short* S1 = Xb + NX;              // Wg bf16 -> later Wd bf16
    unsigned short* S2 = S1 + NW;              // Wu bf16
    unsigned short* S3 = S2 + NW;              // t = silu(g)*u bf16
    // peak ws need: (NX + 3*NW)*2 = 304,087,040 bytes (same as R13)

    dim3 blk512(512);
    dim3 blk256(256);
    const int CG = 2048;

    cvt_f32_bf16<<<CG, blk256, 0, stream>>>(x,  Xb, (int)(NX / 4));
    cvt_f32_bf16<<<CG, blk256, 0, stream>>>(wg, S1, (int)(NW / 4));
    cvt_f32_bf16<<<CG, blk256, 0, stream>>>(wu, S2, (int)(NW / 4));
    // fused gate+up: t = silu(x@Wg^T+bg)*(x@Wu^T+bu)  grid 16*86=1376 (%8==0)
    gemm_gu<<<dim3(16 * 86), blk512, 0, stream>>>(Xb, S1, S2, bg, bu, S3,
                                                  M_TOK, INT_, HID);
    cvt_f32_bf16<<<CG, blk256, 0, stream>>>(wd, S1, (int)(NW / 4));   // Wg dead
    // down: out = t @ Wd^T + bd  (fp32)  grid 16*16=256 (%8==0), NT=172
    gemm_dn<<<dim3(16 * 16), blk512, 0, stream>>>(S3, S1, bd, (float*)d_out,
                                                  M_TOK, HID, INT_);
}

// Round 16
// 997.051 us; speedup vs baseline: 1.5617x; 1.0253x over previous
//
#include <hip/hip_runtime.h>
#include <hip/hip_bf16.h>

// SwiGLU MLP: out = down( silu(x@Wg^T + bg) * (x@Wu^T + bu) ) + bd
// M=4096 tokens, H=4096, I=11008. fp32 in/out, bf16 MFMA compute.
// R16 = R13 (best: 1013us) + tail-fill fusion:
//  (1) wd fp32->bf16 conversion runs as 128 EXTRA blocks of gemm_gu (ids >=
//      1376, dispatched last -> they fill gu's ragged final round: 1376 blocks
//      = 5.375/CU means the last round has only 96/256 CUs busy). Guarded by
//      ws_size >= 394MB; falls back to R13's sequential cvt path.
//  (2) x+wg+wu converts merged into ONE kernel (3 dispatches -> 1).
// gu/dn inner loops, bn-minor mapping, semi-drift 2-sync/tile schedule,
// conflict-free XOR slot-swizzle, XCD bijective swizzle: all R13-verbatim.

#define M_TOK 4096
#define HID   4096
#define INT_  11008
#define NGU   1376          // 16 * 86 gu tiles (%8==0)
#define NCVT  128           // wd-convert tail blocks

typedef __attribute__((ext_vector_type(8))) short bf16x8;
typedef __attribute__((ext_vector_type(4))) float f32x4;

__device__ __forceinline__ unsigned short f2bf(float f) {
    union { float f; unsigned int u; } a; a.f = f;
    unsigned int u = a.u;
    u += 0x7fff + ((u >> 16) & 1);   // RNE
    return (unsigned short)(u >> 16);
}

// ---------------- combined fp32 -> bf16 convert: x, wg, wu in one launch -------
__global__ void cvt3(const float* __restrict__ x,  unsigned short* __restrict__ xb,
                     const float* __restrict__ wg, unsigned short* __restrict__ s1,
                     const float* __restrict__ wu, unsigned short* __restrict__ s2,
                     int n4x, int n4w) {
    const int total = n4x + 2 * n4w;
    const int stride = gridDim.x * blockDim.x;
    for (int i = blockIdx.x * blockDim.x + threadIdx.x; i < total; i += stride) {
        const float* src; unsigned short* dst; int j;
        if (i < n4x)            { j = i;             src = x;  dst = xb; }
        else if (i < n4x + n4w) { j = i - n4x;       src = wg; dst = s1; }
        else                    { j = i - n4x - n4w; src = wu; dst = s2; }
        float4 v = ((const float4*)src)[j];
        ushort4 o;
        o.x = f2bf(v.x); o.y = f2bf(v.y); o.z = f2bf(v.z); o.w = f2bf(v.w);
        ((ushort4*)dst)[j] = o;
    }
}

// ---------------- standalone fp32 -> bf16 (fallback path for wd) ---------------
__global__ void cvt_f32_bf16(const float* __restrict__ in, unsigned short* __restrict__ out, int n4) {
    int stride = gridDim.x * blockDim.x;
    for (int i = blockIdx.x * blockDim.x + threadIdx.x; i < n4; i += stride) {
        float4 v = ((const float4*)in)[i];
        ushort4 o;
        o.x = f2bf(v.x); o.y = f2bf(v.y); o.z = f2bf(v.z); o.w = f2bf(v.w);
        ((ushort4*)out)[i] = o;
    }
}

#define GLL(gsrc, ldst) \
    __builtin_amdgcn_global_load_lds( \
        (__attribute__((address_space(1))) void*)(gsrc), \
        (__attribute__((address_space(3))) void*)(ldst), 16, 0, 0)

#define VMC(n) asm volatile("s_waitcnt vmcnt(" #n ")" ::: "memory")
#define BARR __builtin_amdgcn_s_barrier()
#define PIN  __builtin_amdgcn_sched_barrier(0)

// ================= FUSED gate+up (+ wd-convert tail blocks) ====================
// x: M x K bf16 row-major; Wg,Wu: I x K bf16 row-major; out t: M x I bf16.
// Blocks [0,NGU): GEMM tile 256(M) x 128(I), BK=64, 8 waves (2Mx4N).
// Blocks [NGU, NGU+NCVT): convert wd fp32->bf16 (each 88064 float4 units).
// LDS/buffer (shorts): A-half0 [0,8192) A-half1 [8192,16384)
//                      Bg [16384,24576)  Bu [24576,32768).  dbuf = 128 KiB.
// Within a row, 16B slot s stored at s^(r&7) (0 bank conflicts, R9-verified).
__global__ __launch_bounds__(512, 2)
void gemm_gu(const unsigned short* __restrict__ A,
             const unsigned short* __restrict__ Wg,
             const unsigned short* __restrict__ Wu,
             const float* __restrict__ bg,
             const float* __restrict__ bu,
             unsigned short* __restrict__ T,
             const float* __restrict__ wdSrc,      // fp32 wd (tail blocks)
             unsigned short* __restrict__ wdDst,   // bf16 wd out (tail blocks)
             int M, int NI, int K) {
    __shared__ unsigned short lds[2 * 32768];   // 128 KiB

    const int tid  = threadIdx.x;

    // ---- wd-convert tail blocks (dispatched last -> fill gu's ragged round) ----
    if (blockIdx.x >= NGU) {
        const int c = blockIdx.x - NGU;            // 0..127
        const size_t base = (size_t)c * 88064;     // float4 units; 128*88064*4 == I*H
        const float4* src = (const float4*)wdSrc + base;
        ushort4* dst = (ushort4*)wdDst + base;
#pragma unroll 4
        for (int it = 0; it < 172; ++it) {         // 172*512 == 88064
            const int u = it * 512 + tid;
            float4 v = src[u];
            ushort4 o;
            o.x = f2bf(v.x); o.y = f2bf(v.y); o.z = f2bf(v.z); o.w = f2bf(v.w);
            dst[u] = o;
        }
        return;
    }

    const int lane = tid & 63;
    const int w    = tid >> 6;
    const int wm   = w >> 2;         // 0..1  (128 rows)
    const int wn   = w & 3;          // 0..3  (32 inter-cols)

    // XCD-aware bijective swizzle over the NGU gemm blocks (NGU % 8 == 0)
    const int ntn = NI >> 7;                    // 86
    const int chunk = NGU >> 3;                 // 172
    const int sw = (blockIdx.x & 7) * chunk + (blockIdx.x >> 3);
    const int bm = sw / ntn, bn = sw % ntn;

    const unsigned short* Ag  = A  + (size_t)(bm * 256) * K;
    const unsigned short* Bgg = Wg + (size_t)(bn * 128) * K;
    const unsigned short* Bug = Wu + (size_t)(bn * 128) * K;

    // staging source offsets (pre-swizzled; LDS dest linear)
    int offA[2][2], offBW[2];
#pragma unroll
    for (int i = 0; i < 2; ++i) {
        int sig = i * 512 + tid;
        int r   = sig >> 3;            // packed row 0..127
        int s   = (sig & 7) ^ (r & 7); // logical 16B slot
#pragma unroll
        for (int h = 0; h < 2; ++h) {
            int grow = ((r >> 6) * 2 + h) * 64 + (r & 63);
            offA[h][i] = grow * K + s * 8;
        }
        offBW[i] = r * K + s * 8;      // B rows map 1:1
    }

    // ds_read fragment addressing (swizzled slots)
    const int rl = lane & 15;
    const int kg = lane >> 4;
    const int x  = rl & 7;
    const int aRow  = (wm * 64 + rl) * 64;
    const int bGoff = 16384 + (wn * 32 + rl) * 64;
    const int bUoff = 24576 + (wn * 32 + rl) * 64;
    int slt[2];
#pragma unroll
    for (int ks = 0; ks < 2; ++ks) slt[ks] = ((ks * 4 + kg) ^ x) * 8;

    f32x4 accg[2][8], accu[2][8];     // [qm][fm*2+fn]
#pragma unroll
    for (int q = 0; q < 2; ++q)
#pragma unroll
        for (int f = 0; f < 8; ++f) {
            accg[q][f] = (f32x4){0.f, 0.f, 0.f, 0.f};
            accu[q][f] = (f32x4){0.f, 0.f, 0.f, 0.f};
        }

    const int NT = K >> 6;

#define STAGE_A(H, DST, SRC) \
    GLL((SRC) + offA[H][0], (DST) + (H) * 8192 + tid * 8); \
    GLL((SRC) + offA[H][1], (DST) + (H) * 8192 + 4096 + tid * 8)
#define STAGE_W(BASE, DST, SRC) \
    GLL((SRC) + offBW[0], (DST) + (BASE) + tid * 8); \
    GLL((SRC) + offBW[1], (DST) + (BASE) + 4096 + tid * 8)

#define RD_A(BUF, QM, DST) \
    { _Pragma("unroll") for (int ks = 0; ks < 2; ++ks) \
      _Pragma("unroll") for (int fm = 0; fm < 4; ++fm) \
        DST[ks * 4 + fm] = *(const bf16x8*)((BUF) + (QM) * 8192 + aRow + fm * 1024 + slt[ks]); }
#define RD_W(BUF, ROFF, DST) \
    { _Pragma("unroll") for (int ks = 0; ks < 2; ++ks) \
      _Pragma("unroll") for (int fn = 0; fn < 2; ++fn) \
        DST[ks * 2 + fn] = *(const bf16x8*)((BUF) + (ROFF) + fn * 1024 + slt[ks]); }
#define Q16(ACC, QM, AF, BF) \
    { _Pragma("unroll") for (int ks = 0; ks < 2; ++ks) \
      _Pragma("unroll") for (int fm = 0; fm < 4; ++fm) \
      _Pragma("unroll") for (int fn = 0; fn < 2; ++fn) \
        ACC[QM][fm * 2 + fn] = __builtin_amdgcn_mfma_f32_16x16x32_bf16( \
            AF[ks * 4 + fm], BF[ks * 2 + fn], ACC[QM][fm * 2 + fn], 0, 0, 0); }

    bf16x8 A0f[8], A1f[8], Bgf[4], Buf_[4];

    // prologue: stage tile 0 as A0,Bg,Bu,A1; establish invariant (only A1 in flight)
    STAGE_A(0, lds, Ag);
    STAGE_W(16384, lds, Bgg);
    STAGE_W(24576, lds, Bug);
    STAGE_A(1, lds, Ag);
    VMC(2);
    BARR; PIN;

    for (int t = 0; t < NT; ++t) {
        const unsigned short* bc = lds + (t & 1) * 32768;
        unsigned short* sb = lds + ((t + 1) & 1) * 32768;
        const int ts = (t + 1 < NT) ? (t + 1) : (NT - 1);
        const unsigned short* sA = Ag + (size_t)ts * 64;
        const unsigned short* sG = Bgg + (size_t)ts * 64;
        const unsigned short* sU = Bug + (size_t)ts * 64;

        // chunk1: A0,Bg,Bu proven; 32 MFMA; stage A0,Bg,Bu(t+1)
        RD_A(bc, 0, A0f);
        RD_W(bc, bGoff, Bgf);
        STAGE_A(0, sb, sA);
        Q16(accg, 0, A0f, Bgf);
        RD_W(bc, bUoff, Buf_);
        STAGE_W(16384, sb, sG);
        Q16(accu, 0, A0f, Buf_);
        STAGE_W(24576, sb, sU);
        VMC(6);                         // retires t.A1
        BARR; PIN;

        // chunk2: A1 proven; 32 MFMA; stage A1(t+1)
        RD_A(bc, 1, A1f);
        STAGE_A(1, sb, sA);
        Q16(accg, 1, A1f, Bgf);
        Q16(accu, 1, A1f, Buf_);
        VMC(2);                         // retires t+1.A0,Bg,Bu
        BARR; PIN;
    }
#undef RD_A
#undef RD_W
#undef Q16
#undef STAGE_A
#undef STAGE_W

    // epilogue: C/D layout col=lane&15, row=(lane>>4)*4+j; t = silu(g)*u -> bf16
    const int rbase = bm * 256 + wm * 128 + (lane >> 4) * 4;
    const int cbase = bn * 128 + wn * 32 + (lane & 15);
#pragma unroll
    for (int qm = 0; qm < 2; ++qm)
#pragma unroll
        for (int fn = 0; fn < 2; ++fn) {
            const int col = cbase + fn * 16;
            const float bgv = bg[col];
            const float buv = bu[col];
#pragma unroll
            for (int fm = 0; fm < 4; ++fm) {
                const int rb = rbase + qm * 64 + fm * 16;
#pragma unroll
                for (int j = 0; j < 4; ++j) {
                    float g = accg[qm][fm * 2 + fn][j] + bgv;
                    float u = accu[qm][fm * 2 + fn][j] + buv;
                    float s = g / (1.f + __expf(-g)) * u;
                    T[(size_t)(rb + j) * (size_t)INT_ + col] = f2bf(s);
                }
            }
        }
}

// ================= down GEMM (R11 verbatim, fp32 epilogue) ======================
__global__ __launch_bounds__(512, 2)
void gemm_dn(const unsigned short* __restrict__ A,
             const unsigned short* __restrict__ B,
             const float* __restrict__ bias,
             float* __restrict__ C,
             int M, int N, int K) {
    __shared__ unsigned short lds[2 * 32768];   // 128 KiB

    const int tid  = threadIdx.x;
    const int lane = tid & 63;
    const int w    = tid >> 6;
    const int wm   = w >> 2;
    const int wn   = w & 3;

    const int ntn = N >> 8;
    const int chunk = gridDim.x >> 3;
    const int sw = (blockIdx.x & 7) * chunk + (blockIdx.x >> 3);
    const int bm = sw / ntn, bn = sw % ntn;

    const unsigned short* Ag = A + (size_t)(bm * 256) * K;
    const unsigned short* Bg = B + (size_t)(bn * 256) * K;

    int offA[2][2], offB[2][2];
#pragma unroll
    for (int h = 0; h < 2; ++h)
#pragma unroll
        for (int i = 0; i < 2; ++i) {
            int sig = i * 512 + tid;
            int r   = sig >> 3;
            int s   = (sig & 7) ^ (r & 7);
            int grow = ((r >> 6) * 2 + h) * 64 + (r & 63);
            int gcol = ((r >> 5) * 2 + h) * 32 + (r & 31);
            offA[h][i] = grow * K + s * 8;
            offB[h][i] = gcol * K + s * 8;
        }

    const int rl = lane & 15;
    const int kg = lane >> 4;
    const int x  = rl & 7;
    const int aRow = (wm * 64 + rl) * 64;
    const int bRow = 16384 + (wn * 32 + rl) * 64;
    int slt[2];
#pragma unroll
    for (int ks = 0; ks < 2; ++ks) slt[ks] = ((ks * 4 + kg) ^ x) * 8;

    f32x4 acc[2][2][8];
#pragma unroll
    for (int qm = 0; qm < 2; ++qm)
#pragma unroll
        for (int qn = 0; qn < 2; ++qn)
#pragma unroll
            for (int f = 0; f < 8; ++f)
                acc[qm][qn][f] = (f32x4){0.f, 0.f, 0.f, 0.f};

    const int NT = K >> 6;

#define STAGE_A(H, DST, SRC) \
    GLL((SRC) + offA[H][0], (DST) + (H) * 8192 + tid * 8); \
    GLL((SRC) + offA[H][1], (DST) + (H) * 8192 + 4096 + tid * 8)
#define STAGE_B(H, DST, SRC) \
    GLL((SRC) + offB[H][0], (DST) + 16384 + (H) * 8192 + tid * 8); \
    GLL((SRC) + offB[H][1], (DST) + 16384 + (H) * 8192 + 4096 + tid * 8)
#define RD_A(BUF, QM, DST) \
    { _Pragma("unroll") for (int ks = 0; ks < 2; ++ks) \
      _Pragma("unroll") for (int fm = 0; fm < 4; ++fm) \
        DST[ks * 4 + fm] = *(const bf16x8*)((BUF) + (QM) * 8192 + aRow + fm * 1024 + slt[ks]); }
#define RD_B(BUF, QN, DST) \
    { _Pragma("unroll") for (int ks = 0; ks < 2; ++ks) \
      _Pragma("unroll") for (int fn = 0; fn < 2; ++fn) \
        DST[ks * 2 + fn] = *(const bf16x8*)((BUF) + (QN) * 8192 + bRow + fn * 1024 + slt[ks]); }
#define Q16(QM, QN, AF, BF) \
    { _Pragma("unroll") for (int ks = 0; ks < 2; ++ks) \
      _Pragma("unroll") for (int fm = 0; fm < 4; ++fm) \
      _Pragma("unroll") for (int fn = 0; fn < 2; ++fn) \
        acc[QM][QN][fm * 2 + fn] = __builtin_amdgcn_mfma_f32_16x16x32_bf16( \
            AF[ks * 4 + fm], BF[ks * 2 + fn], acc[QM][QN][fm * 2 + fn], 0, 0, 0); }

    bf16x8 A0f[8], A1f[8], B0f[4], B1f[4];

    STAGE_A(0, lds, Ag); STAGE_B(0, lds, Bg); STAGE_B(1, lds, Bg); STAGE_A(1, lds, Ag);
    VMC(2);
    BARR; PIN;

    for (int t = 0; t < NT; ++t) {
        const unsigned short* bc = lds + (t & 1) * 32768;
        unsigned short* sb = lds + ((t + 1) & 1) * 32768;
        const int ts = (t + 1 < NT) ? (t + 1) : (NT - 1);
        const unsigned short* sAt = Ag + (size_t)ts * 64;
        const unsigned short* sBt = Bg + (size_t)ts * 64;

        RD_A(bc, 0, A0f);
        RD_B(bc, 0, B0f);
        STAGE_A(0, sb, sAt);
        Q16(0, 0, A0f, B0f);
        RD_B(bc, 1, B1f);
        STAGE_B(0, sb, sBt);
        Q16(0, 1, A0f, B1f);
        STAGE_B(1, sb, sBt);
        VMC(6);
        BARR; PIN;

        RD_A(bc, 1, A1f);
        STAGE_A(1, sb, sAt);
        Q16(1, 1, A1f, B1f);
        Q16(1, 0, A1f, B0f);
        VMC(2);
        BARR; PIN;
    }
#undef RD_A
#undef RD_B
#undef Q16
#undef STAGE_A
#undef STAGE_B

    const int rbase = bm * 256 + wm * 128 + (lane >> 4) * 4;
    const int cbase = bn * 256 + wn * 64 + (lane & 15);
#pragma unroll
    for (int qm = 0; qm < 2; ++qm)
#pragma unroll
        for (int qn = 0; qn < 2; ++qn)
#pragma unroll
            for (int fn = 0; fn < 2; ++fn) {
                const int col = cbase + qn * 32 + fn * 16;
                const float bv = bias[col];
#pragma unroll
                for (int fm = 0; fm < 4; ++fm) {
                    const int rb = rbase + qm * 64 + fm * 16;
#pragma unroll
                    for (int j = 0; j < 4; ++j)
                        C[(size_t)(rb + j) * (size_t)N + col] = acc[qm][qn][fm * 2 + fn][j] + bv;
                }
            }
}

// ---------------- launcher ----------------
extern "C" void kernel_launch(void* const* d_in, const int* in_sizes, int n_in,
                              void* d_out, int out_size, void* d_ws, size_t ws_size,
                              hipStream_t stream) {
    const float* x  = (const float*)d_in[0];   // (2,2048,4096)
    const float* wg = (const float*)d_in[1];   // (11008,4096)
    const float* bg = (const float*)d_in[2];
    const float* wu = (const float*)d_in[3];
    const float* bu = (const float*)d_in[4];
    const float* wd = (const float*)d_in[5];   // (4096,11008)
    const float* bd = (const float*)d_in[6];

    const size_t NX = (size_t)M_TOK * HID;     // 16,777,216
    const size_t NW = (size_t)INT_ * HID;      // 45,088,768 (== M_TOK*INT_)

    unsigned short* ws = (unsigned short*)d_ws;
    unsigned short* Xb = ws;                   // x bf16
    unsigned short* S1 = Xb + NX;              // Wg bf16 (fallback: -> Wd later)
    unsigned short* S2 = S1 + NW;              // Wu bf16
    unsigned short* S3 = S2 + NW;              // t = silu(g)*u bf16
    unsigned short* S4 = S3 + NW;              // Wd bf16 (fused path only)

    const bool fused = ws_size >= (NX + 4 * NW) * 2;   // 394,264,576 B

    dim3 blk512(512);
    dim3 blk256(256);

    // x + Wg + Wu converts in one dispatch
    cvt3<<<2048, blk256, 0, stream>>>(x, Xb, wg, S1, wu, S2,
                                      (int)(NX / 4), (int)(NW / 4));

    if (fused) {
        // gu tiles + 128 wd-convert tail blocks (fill the ragged last round)
        gemm_gu<<<dim3(NGU + NCVT), blk512, 0, stream>>>(Xb, S1, S2, bg, bu, S3,
                                                         wd, S4, M_TOK, INT_, HID);
        gemm_dn<<<dim3(16 * 16), blk512, 0, stream>>>(S3, S4, bd, (float*)d_out,
                                                      M_TOK, HID, INT_);
    } else {
        gemm_gu<<<dim3(NGU), blk512, 0, stream>>>(Xb, S1, S2, bg, bu, S3,
                                                  (const float*)nullptr,
                                                  (unsigned short*)nullptr,
                                                  M_TOK, INT_, HID);
        cvt_f32_bf16<<<2048, blk256, 0, stream>>>(wd, S1, (int)(NW / 4));  // Wg dead
        gemm_dn<<<dim3(16 * 16), blk512, 0, stream>>>(S3, S1, bd, (float*)d_out,
                                                      M_TOK, HID, INT_);
    }
}